// Round 14
// baseline (166.351 us; speedup 1.0000x reference)
//
#include <hip/hip_runtime.h>

#define B_  256
#define T_  256
#define S_  20
#define U1  32
#define G1  128   // 4*U1
#define U2  24
#define G2  96    // 4*U2
#define NT  16    // 16-row t-tiles per sequence

typedef __attribute__((ext_vector_type(8))) short short8;   // 8 bf16 = 4 VGPRs
typedef __attribute__((ext_vector_type(4))) float f32x4;    // MFMA acc
typedef __attribute__((ext_vector_type(2))) float f32x2;    // v_pk_fma_f32 pair

__device__ __forceinline__ f32x2 pkfma(f32x2 a, f32x2 b, f32x2 c) {
#if __has_builtin(__builtin_elementwise_fma)
    return __builtin_elementwise_fma(a, b, c);
#else
    f32x2 r; r[0] = __builtin_fmaf(a[0], b[0], c[0]); r[1] = __builtin_fmaf(a[1], b[1], c[1]);
    return r;
#endif
}

// Raw-HW activations (v_exp_f32 = 2^x, pre-scaled by log2e). R7: 134->74us.
__device__ __forceinline__ float sigmoidf_(float x) {
    return __builtin_amdgcn_rcpf(1.0f + __builtin_amdgcn_exp2f(x * -1.44269504f));
}
__device__ __forceinline__ float tanhf_fast(float x) {   // 1 - 2/(1+e^{2x})
    return 1.0f - 2.0f * __builtin_amdgcn_rcpf(1.0f + __builtin_amdgcn_exp2f(x * 2.88539008f));
}

__device__ __forceinline__ unsigned short f2bf(float a) {
    unsigned int u = __float_as_uint(a);
    u += 0x7FFFu + ((u >> 16) & 1u);
    return (unsigned short)(u >> 16);
}
__device__ __forceinline__ unsigned int pack2bf(float a, float b) {
    unsigned int ua = __float_as_uint(a); ua += 0x7FFFu + ((ua >> 16) & 1u);
    unsigned int ub = __float_as_uint(b); ub += 0x7FFFu + ((ub >> 16) & 1u);
    return (ua >> 16) | (ub & 0xFFFF0000u);
}
union frag_u { short8 v; unsigned int u[4]; };
union h2x  { unsigned int u32; _Float16 h[2]; };

// FUSED producer-consumer (R13 topology) + consumer chain surgery:
//  - ALL 4 gates per lane via packed v_pk_fma_f32 (48 pk-FMAs = same issue as
//    the half-split's 48 scalar FMAs) -> NO shfl_xor (~130cyc DS latency was
//    on the 256-step serial chain in R8-R13), no cndmask gate selects.
//  - tile-wise consumer loop: flag wait + cross-tile prefetch once per 16
//    steps; the hot loop has no clamps/tile checks.
// 256 thr = 4 waves, 1 wave/EU (waves_per_eu(1,1) keeps 96 weight VGPRs
// resident -- proven R9). Wave 0: produce tile 0 then consume. Waves 1-3:
// tiles {w, w+3, w+6, w+9, w+12} in consumption order; per-tile LDS flags.
__global__ __attribute__((amdgpu_flat_work_group_size(256, 256)))
__attribute__((amdgpu_waves_per_eu(1, 1)))
void fused_kernel(
    const float* __restrict__ x,        // [B*T*S]
    const int*   __restrict__ lengths,  // [B]
    const float* __restrict__ Wi,       // [G1]
    const float* __restrict__ Ui,       // [U1*G1]
    const float* __restrict__ bi,       // [G1]
    const float* __restrict__ Wo,       // [U1*G2]
    const float* __restrict__ Uo,       // [U2*G2]
    const float* __restrict__ bo,       // [G2]
    const float* __restrict__ Wd,       // [U2]
    const float* __restrict__ bd,       // [1]
    float* __restrict__ out)            // [B]
{
    __shared__ __align__(16) _Float16      Pl[T_][G2];      // [t][u*4+g], 48 KB
    __shared__ __align__(16) unsigned short hbb[4][16][40]; // per-wave h tiles
    __shared__ unsigned int flags[NT];
    const int b    = blockIdx.x;
    const int len  = lengths[b];                 // >= 1
    const int tid  = threadIdx.x;
    const int w    = __builtin_amdgcn_readfirstlane(tid >> 6);   // wave 0..3
    const int lane = tid & 63;
    const int q    = lane >> 4;
    const int n    = lane & 15;

    if (tid < NT) flags[tid] = 0;
    __syncthreads();                             // only barrier: flag init

    // ---- one-time fragment/bias loads ----
    frag_u Bui[8];
#pragma unroll
    for (int tt = 0; tt < 8; ++tt)
#pragma unroll
        for (int k2 = 0; k2 < 4; ++k2)
            Bui[tt].u[k2] = pack2bf(Ui[(8 * q + 2 * k2) * G1 + 16 * tt + n],
                                    Ui[(8 * q + 2 * k2 + 1) * G1 + 16 * tt + n]);
    frag_u Bwo[6];
#pragma unroll
    for (int tt = 0; tt < 6; ++tt)
#pragma unroll
        for (int k2 = 0; k2 < 4; ++k2)
            Bwo[tt].u[k2] = pack2bf(Wo[(8 * q + 2 * k2) * G2 + 16 * tt + n],
                                    Wo[(8 * q + 2 * k2 + 1) * G2 + 16 * tt + n]);
    float bi_l[8], Wi_l[8], bo_l[6];
#pragma unroll
    for (int tt = 0; tt < 8; ++tt) { bi_l[tt] = bi[16 * tt + n]; Wi_l[tt] = Wi[16 * tt + n]; }
#pragma unroll
    for (int tt = 0; tt < 6; ++tt) bo_l[tt] = bo[16 * tt + n];
    // P-store targets: col=16tt+n -> (g=col/24, u=col%24) -> offset u*4+g
    int pcol[6];
#pragma unroll
    for (int tt = 0; tt < 6; ++tt) {
        const int col = 16 * tt + n;
        const int g = col / 24;
        pcol[tt] = (col - 24 * g) * 4 + g;
    }

    // ---- producer worklists (consumption order) ----
    const int ntl = (w == 0) ? 1 : 5;
#pragma unroll 1
    for (int i = 0; i < ntl; ++i) {
        const int tile = (w == 0) ? 0 : (w + 3 * i);
        const int wt0  = tile * 16;
        if (wt0 >= len) break;                   // list increasing: rest masked too

        const float* xr = x + (size_t)(b * T_ + wt0 + 4 * q) * S_;
        float c[2][4];
#pragma unroll
        for (int uh = 0; uh < 2; ++uh)
#pragma unroll
            for (int r = 0; r < 4; ++r) c[uh][r] = 0.0f;

        float xc[4];
#pragma unroll
        for (int r = 0; r < 4; ++r) xc[r] = xr[r * S_];

        // peeled s = 0 (h == 0: no MFMA)
        {
            f32x4 acc[8];
#pragma unroll
            for (int tt = 0; tt < 8; ++tt)
#pragma unroll
                for (int r = 0; r < 4; ++r)
                    acc[tt][r] = bi_l[tt] + xc[r] * Wi_l[tt];
#pragma unroll
            for (int uh = 0; uh < 2; ++uh)
#pragma unroll
                for (int r = 0; r < 4; ++r) {
                    const float iv = sigmoidf_(acc[0 + uh][r]);
                    const float fv = sigmoidf_(acc[2 + uh][r]);
                    const float gv = tanhf_fast(acc[4 + uh][r]);
                    const float ov = sigmoidf_(acc[6 + uh][r]);
                    c[uh][r] = fv * c[uh][r] + iv * gv;
                    hbb[w][4 * q + r][n + 16 * uh] = f2bf(ov * tanhf_fast(c[uh][r]));
                }
        }
#pragma unroll
        for (int r = 0; r < 4; ++r) xc[r] = xr[r * S_ + 1];

        // steady state s = 1..19
#pragma unroll 1
        for (int s = 1; s < S_; ++s) {
            const int sn = (s + 1 < S_) ? s + 1 : S_ - 1;
            float xnx[4];
#pragma unroll
            for (int r = 0; r < 4; ++r) xnx[r] = xr[r * S_ + sn];

            f32x4 acc[8];
#pragma unroll
            for (int tt = 0; tt < 8; ++tt)
#pragma unroll
                for (int r = 0; r < 4; ++r)
                    acc[tt][r] = bi_l[tt] + xc[r] * Wi_l[tt];

            const short8 A = *(const short8*)&hbb[w][n][8 * q];
#pragma unroll
            for (int tt = 0; tt < 8; ++tt)
                acc[tt] = __builtin_amdgcn_mfma_f32_16x16x32_bf16(A, Bui[tt].v, acc[tt], 0, 0, 0);

#pragma unroll
            for (int uh = 0; uh < 2; ++uh)
#pragma unroll
                for (int r = 0; r < 4; ++r) {
                    const float iv = sigmoidf_(acc[0 + uh][r]);
                    const float fv = sigmoidf_(acc[2 + uh][r]);
                    const float gv = tanhf_fast(acc[4 + uh][r]);
                    const float ov = sigmoidf_(acc[6 + uh][r]);
                    c[uh][r] = fv * c[uh][r] + iv * gv;
                    hbb[w][4 * q + r][n + 16 * uh] = f2bf(ov * tanhf_fast(c[uh][r]));
                }
#pragma unroll
            for (int r = 0; r < 4; ++r) xc[r] = xnx[r];
        }

        // P tile = bo + h @ Wo -> LDS, unit-major pair layout
        {
            const short8 A = *(const short8*)&hbb[w][n][8 * q];
            f32x4 accp[6];
#pragma unroll
            for (int tt = 0; tt < 6; ++tt) {
#pragma unroll
                for (int r = 0; r < 4; ++r) accp[tt][r] = bo_l[tt];
                accp[tt] = __builtin_amdgcn_mfma_f32_16x16x32_bf16(A, Bwo[tt].v, accp[tt], 0, 0, 0);
            }
#pragma unroll
            for (int r = 0; r < 4; ++r) {
                const int tr = wt0 + 4 * q + r;
#pragma unroll
                for (int tt = 0; tt < 6; ++tt)
                    Pl[tr][pcol[tt]] = (_Float16)accp[tt][r];
            }
        }
        __hip_atomic_store(&flags[tile], 1u, __ATOMIC_RELEASE, __HIP_MEMORY_SCOPE_WORKGROUP);
    }

    if (w != 0) return;                          // producers retire

    // ======== phase 2: outer LSTM + head (wave 0) ==========================
    const int u = (lane < U2) ? lane : U2 - 1;

    // all 4 gates per lane, weights as packed pairs: (i,f) and (g,o)
    f32x2 wIF[U2], wGO[U2];                      // 96 weight VGPRs, resident
#pragma unroll
    for (int k = 0; k < U2; ++k) {
        wIF[k][0] = Uo[k * G2 + 0 * U2 + u];
        wIF[k][1] = Uo[k * G2 + 1 * U2 + u];
        wGO[k][0] = Uo[k * G2 + 2 * U2 + u];
        wGO[k][1] = Uo[k * G2 + 3 * U2 + u];
    }

    // one ds_read_b64 per row: (i,f,g,o) pre-activations of unit u
    auto ldrow = [&](int t) -> f32x4 {
        const uint2 raw = *reinterpret_cast<const uint2*>(&Pl[t][4 * u]);
        h2x a, c2; a.u32 = raw.x; c2.u32 = raw.y;
        f32x4 r;
        r[0] = (float)a.h[0];  r[1] = (float)a.h[1];   // i, f
        r[2] = (float)c2.h[0]; r[3] = (float)c2.h[1];  // g, o
        return r;
    };

    float cu, hu;
    {   // peeled t = 0 (h == 0, c == 0) -- all gates lane-local, no shuffles
        const f32x4 r0 = ldrow(0);               // tile 0 self-produced
        const float ig = sigmoidf_(r0[0]);
        const float gg = tanhf_fast(r0[2]);
        const float og = sigmoidf_(r0[3]);
        cu = ig * gg;
        hu = og * tanhf_fast(cu);
    }

    int t = 1, tile = 0;
    int tend = (16 < len) ? 16 : len;
    f32x4 nxt = ldrow((1 < len) ? 1 : 0);

#pragma unroll 1
    while (t < len) {
        // hot loop: rows t .. tend-2 (prefetch stays inside this tile)
#pragma unroll 1
        for (; t + 1 < tend; ++t) {
            const f32x4 pf = ldrow(t + 1);       // in-tile prefetch (off-chain)

            f32x2 zIF0 = { nxt[0], nxt[1] }, zIF1 = { 0.0f, 0.0f };
            f32x2 zGO0 = { nxt[2], nxt[3] }, zGO1 = { 0.0f, 0.0f };
#pragma unroll
            for (int k = 0; k < U2; k += 2) {
                const float h0 = __int_as_float(__builtin_amdgcn_readlane(__float_as_int(hu), k));
                const float h1 = __int_as_float(__builtin_amdgcn_readlane(__float_as_int(hu), k + 1));
                const f32x2 h02 = { h0, h0 }, h12 = { h1, h1 };
                zIF0 = pkfma(wIF[k],     h02, zIF0);
                zGO0 = pkfma(wGO[k],     h02, zGO0);
                zIF1 = pkfma(wIF[k + 1], h12, zIF1);
                zGO1 = pkfma(wGO[k + 1], h12, zGO1);
            }
            const f32x2 zIF = zIF0 + zIF1;
            const f32x2 zGO = zGO0 + zGO1;

            const float ig = sigmoidf_(zIF[0]);
            const float fg = sigmoidf_(zIF[1]);
            const float gg = tanhf_fast(zGO[0]);
            const float og = sigmoidf_(zGO[1]);
            cu = fg * cu + ig * gg;
            hu = og * tanhf_fast(cu);
            nxt = pf;
        }

        // boundary row t == tend-1: fetch next tile's first row first
        f32x4 pf = nxt;                          // placate: reused below
        const bool more = (tend < len);
        if (more) {                              // wave-uniform
            ++tile;
            while (__hip_atomic_load(&flags[tile], __ATOMIC_ACQUIRE,
                                     __HIP_MEMORY_SCOPE_WORKGROUP) == 0u)
                __builtin_amdgcn_s_sleep(1);
            pf = ldrow(tend);                    // latency hidden under the step
        }
        {
            f32x2 zIF0 = { nxt[0], nxt[1] }, zIF1 = { 0.0f, 0.0f };
            f32x2 zGO0 = { nxt[2], nxt[3] }, zGO1 = { 0.0f, 0.0f };
#pragma unroll
            for (int k = 0; k < U2; k += 2) {
                const float h0 = __int_as_float(__builtin_amdgcn_readlane(__float_as_int(hu), k));
                const float h1 = __int_as_float(__builtin_amdgcn_readlane(__float_as_int(hu), k + 1));
                const f32x2 h02 = { h0, h0 }, h12 = { h1, h1 };
                zIF0 = pkfma(wIF[k],     h02, zIF0);
                zGO0 = pkfma(wGO[k],     h02, zGO0);
                zIF1 = pkfma(wIF[k + 1], h12, zIF1);
                zGO1 = pkfma(wGO[k + 1], h12, zGO1);
            }
            const f32x2 zIF = zIF0 + zIF1;
            const f32x2 zGO = zGO0 + zGO1;

            const float ig = sigmoidf_(zIF[0]);
            const float fg = sigmoidf_(zIF[1]);
            const float gg = tanhf_fast(zGO[0]);
            const float og = sigmoidf_(zGO[1]);
            cu = fg * cu + ig * gg;
            hu = og * tanhf_fast(cu);
        }
        ++t;
        nxt = pf;
        tend = (tend + 16 < len) ? tend + 16 : len;
    }

    // dense sigmoid head
    float acc = bd[0];
#pragma unroll
    for (int k = 0; k < U2; ++k)
        acc += __int_as_float(__builtin_amdgcn_readlane(__float_as_int(hu), k)) * Wd[k];
    if (lane == 0) out[b] = sigmoidf_(acc);
}

extern "C" void kernel_launch(void* const* d_in, const int* in_sizes, int n_in,
                              void* d_out, int out_size, void* d_ws, size_t ws_size,
                              hipStream_t stream) {
    const float* x       = (const float*)d_in[0];
    const int*   lengths = (const int*)  d_in[1];
    const float* Wi      = (const float*)d_in[2];
    const float* Ui      = (const float*)d_in[3];
    const float* bi      = (const float*)d_in[4];
    const float* Wo      = (const float*)d_in[5];
    const float* Uo      = (const float*)d_in[6];
    const float* bo      = (const float*)d_in[7];
    const float* Wd      = (const float*)d_in[8];
    const float* bd      = (const float*)d_in[9];
    float* out = (float*)d_out;

    fused_kernel<<<dim3(B_), dim3(256), 0, stream>>>(
        x, lengths, Wi, Ui, bi, Wo, Uo, bo, Wd, bd, out);
}